// Round 1
// baseline (433.710 us; speedup 1.0000x reference)
//
#include <hip/hip_runtime.h>
#include <math.h>

#define FDIM 128
#define CDIM 40

// ---------------------------------------------------------------------------
// Graph preprocessing: degree (incl. self-loop), dinv = rsqrt(deg), CSR by dst
// ---------------------------------------------------------------------------

__global__ void k_init(float* __restrict__ deg, int* __restrict__ row_cur, int n) {
    int i = blockIdx.x * blockDim.x + threadIdx.x;
    if (i < n) { deg[i] = 1.0f; row_cur[i] = 0; }   // 1.0 = self-loop
}

__global__ void k_count(const int* __restrict__ dst, float* __restrict__ deg, int e) {
    int i = blockIdx.x * blockDim.x + threadIdx.x;
    if (i < e) atomicAdd(&deg[dst[i]], 1.0f);
}

__global__ void k_dinv(const float* __restrict__ deg, float* __restrict__ dinv, int n) {
    int i = blockIdx.x * blockDim.x + threadIdx.x;
    if (i < n) dinv[i] = rsqrtf(deg[i]);
}

// Exclusive scan of (deg[i]-1) -> row_ptr. Single block of 1024 threads,
// Hillis-Steele per 1024-chunk with running carry. N=10000 -> 10 chunks.
__global__ void k_scan(const float* __restrict__ deg, int* __restrict__ row_ptr, int n) {
    __shared__ int sdata[1024];
    int carry = 0;
    for (int base = 0; base < n; base += 1024) {
        int i = base + (int)threadIdx.x;
        int v = (i < n) ? ((int)deg[i] - 1) : 0;
        sdata[threadIdx.x] = v;
        __syncthreads();
        for (int off = 1; off < 1024; off <<= 1) {
            int t = (threadIdx.x >= (unsigned)off) ? sdata[threadIdx.x - off] : 0;
            __syncthreads();
            sdata[threadIdx.x] += t;
            __syncthreads();
        }
        if (i < n) row_ptr[i] = carry + sdata[threadIdx.x] - v;  // exclusive
        carry += sdata[1023];
        __syncthreads();
    }
    if (threadIdx.x == 0) row_ptr[n] = carry;
}

__global__ void k_fill(const int* __restrict__ src, const int* __restrict__ dst,
                       const int* __restrict__ row_ptr, int* __restrict__ row_cur,
                       int* __restrict__ col_src, int e) {
    int i = blockIdx.x * blockDim.x + threadIdx.x;
    if (i < e) {
        int d = dst[i];
        int pos = row_ptr[d] + atomicAdd(&row_cur[d], 1);
        col_src[pos] = src[i];
    }
}

// ---------------------------------------------------------------------------
// GEMM: out[n,128] = A[n,128] @ W[128,128]   (no bias; bias fused into agg)
// Block = 256 threads handles 8 rows x 128 cols. A-tile staged in LDS; W is
// 64 KB and L2-resident, loaded coalesced (128 consecutive cols per wave).
// ---------------------------------------------------------------------------
__global__ void k_gemm128(const float* __restrict__ A, const float* __restrict__ W,
                          float* __restrict__ out, int n) {
    __shared__ float As[8][FDIM];
    int block_row = blockIdx.x * 8;
    int tid = threadIdx.x;
    for (int t = tid; t < 8 * FDIM; t += 256) {
        int r = t >> 7, c = t & 127;
        int gr = block_row + r;
        As[r][c] = (gr < n) ? A[(size_t)gr * FDIM + c] : 0.0f;
    }
    __syncthreads();
    int col = tid & 127;
    int rbase = (tid >> 7) * 4;  // 0 or 4
    float acc0 = 0.f, acc1 = 0.f, acc2 = 0.f, acc3 = 0.f;
    for (int k = 0; k < FDIM; ++k) {
        float w = W[k * FDIM + col];
        // As[r][k]: all lanes read the same address -> LDS broadcast, free
        acc0 += As[rbase + 0][k] * w;
        acc1 += As[rbase + 1][k] * w;
        acc2 += As[rbase + 2][k] * w;
        acc3 += As[rbase + 3][k] * w;
    }
    int r0 = block_row + rbase;
    if (r0 + 0 < n) out[(size_t)(r0 + 0) * FDIM + col] = acc0;
    if (r0 + 1 < n) out[(size_t)(r0 + 1) * FDIM + col] = acc1;
    if (r0 + 2 < n) out[(size_t)(r0 + 2) * FDIM + col] = acc2;
    if (r0 + 3 < n) out[(size_t)(r0 + 3) * FDIM + col] = acc3;
}

// ---------------------------------------------------------------------------
// Aggregation: out[i] = maybe_relu( dinv[i]*sum_{s in N(i)} dinv[s]*h[s]
//                                   + dinv[i]^2*h[i] + bias )
// 256 threads = 2 nodes x 128 feature-lanes. Gathers are 512B coalesced rows.
// ---------------------------------------------------------------------------
template <bool RELU>
__global__ void k_agg(const float* __restrict__ h, const float* __restrict__ dinv,
                      const int* __restrict__ row_ptr, const int* __restrict__ col_src,
                      const float* __restrict__ bias, float* __restrict__ out, int n) {
    int node = blockIdx.x * 2 + (threadIdx.x >> 7);
    int f = threadIdx.x & 127;
    if (node >= n) return;
    int beg = row_ptr[node];
    int end = row_ptr[node + 1];
    float acc = 0.0f;
    for (int j = beg; j < end; ++j) {
        int s = col_src[j];
        acc += dinv[s] * h[(size_t)s * FDIM + f];
    }
    float di = dinv[node];
    float v = di * acc + di * di * h[(size_t)node * FDIM + f] + bias[f];
    if (RELU) v = fmaxf(v, 0.0f);
    out[(size_t)node * FDIM + f] = v;
}

// ---------------------------------------------------------------------------
// Classifier + log_softmax: one 64-lane wave per node, lane c < 40 computes
// logit c; shuffle reductions for max and sum(exp).
// ---------------------------------------------------------------------------
__global__ void k_cls(const float* __restrict__ h, const float* __restrict__ Wc,
                      const float* __restrict__ bc, float* __restrict__ out, int n) {
    int node = blockIdx.x * 4 + (int)(threadIdx.x >> 6);
    int lane = threadIdx.x & 63;
    if (node >= n) return;
    const float* hrow = h + (size_t)node * FDIM;
    float acc = 0.0f;
    if (lane < CDIM) {
        acc = bc[lane];
        for (int k = 0; k < FDIM; ++k)
            acc += hrow[k] * Wc[k * CDIM + lane];
    }
    float v = (lane < CDIM) ? acc : -INFINITY;
    float m = v;
    for (int off = 32; off > 0; off >>= 1) m = fmaxf(m, __shfl_down(m, off));
    m = __shfl(m, 0);
    float e = (lane < CDIM) ? expf(v - m) : 0.0f;
    float s = e;
    for (int off = 32; off > 0; off >>= 1) s += __shfl_down(s, off);
    s = __shfl(s, 0);
    if (lane < CDIM) out[(size_t)node * CDIM + lane] = v - m - logf(s);
}

// ---------------------------------------------------------------------------

extern "C" void kernel_launch(void* const* d_in, const int* in_sizes, int n_in,
                              void* d_out, int out_size, void* d_ws, size_t ws_size,
                              hipStream_t stream) {
    const float* x  = (const float*)d_in[0];
    const int*   ei = (const int*)d_in[1];
    const float* W1 = (const float*)d_in[2];
    const float* b1 = (const float*)d_in[3];
    const float* W2 = (const float*)d_in[4];
    const float* b2 = (const float*)d_in[5];
    const float* Wc = (const float*)d_in[6];
    const float* bc = (const float*)d_in[7];
    float* out = (float*)d_out;

    const int N = in_sizes[0] / FDIM;
    const int E = in_sizes[1] / 2;
    const int* srcp = ei;         // edge_index[0]
    const int* dstp = ei + E;     // edge_index[1]

    // Workspace carve-up (poisoned 0xAA each launch -> everything initialized)
    char* ws = (char*)d_ws;
    auto alloc = [&](size_t bytes) {
        char* p = ws;
        ws += (bytes + 255) & ~(size_t)255;
        return p;
    };
    float* deg     = (float*)alloc((size_t)N * 4);
    float* dinv    = (float*)alloc((size_t)N * 4);
    int*   row_ptr = (int*)  alloc((size_t)(N + 1) * 4);
    int*   row_cur = (int*)  alloc((size_t)N * 4);
    int*   col_src = (int*)  alloc((size_t)E * 4);
    float* hbuf    = (float*)alloc((size_t)N * FDIM * 4);
    float* aggbuf  = (float*)alloc((size_t)N * FDIM * 4);

    // Graph build
    k_init <<<(N + 255) / 256, 256, 0, stream>>>(deg, row_cur, N);
    k_count<<<(E + 255) / 256, 256, 0, stream>>>(dstp, deg, E);
    k_dinv <<<(N + 255) / 256, 256, 0, stream>>>(deg, dinv, N);
    k_scan <<<1, 1024, 0, stream>>>(deg, row_ptr, N);
    k_fill <<<(E + 255) / 256, 256, 0, stream>>>(srcp, dstp, row_ptr, row_cur, col_src, E);

    // Layer 1: h = x@W1 ; agg(+b1, relu)
    k_gemm128<<<(N + 7) / 8, 256, 0, stream>>>(x, W1, hbuf, N);
    k_agg<true><<<(N + 1) / 2, 256, 0, stream>>>(hbuf, dinv, row_ptr, col_src, b1, aggbuf, N);

    // Layer 2: h = agg@W2 ; agg(+b2)
    k_gemm128<<<(N + 7) / 8, 256, 0, stream>>>(aggbuf, W2, hbuf, N);
    k_agg<false><<<(N + 1) / 2, 256, 0, stream>>>(hbuf, dinv, row_ptr, col_src, b2, aggbuf, N);

    // Classifier + log_softmax
    k_cls<<<(N + 3) / 4, 256, 0, stream>>>(aggbuf, Wc, bc, out, N);
}

// Round 2
// 273.207 us; speedup vs baseline: 1.5875x; 1.5875x over previous
//
#include <hip/hip_runtime.h>
#include <math.h>

#define FDIM 128
#define CDIM 40

// ---------------------------------------------------------------------------
// Graph preprocessing
// ---------------------------------------------------------------------------

__global__ void k_init(int* __restrict__ deg, int* __restrict__ row_cur, int n) {
    int i = blockIdx.x * blockDim.x + threadIdx.x;
    if (i < n) { deg[i] = 0; row_cur[i] = 0; }
}

__global__ void k_count(const int* __restrict__ dst, int* __restrict__ deg, int e) {
    int i = blockIdx.x * blockDim.x + threadIdx.x;
    if (i < e) atomicAdd(&deg[dst[i]], 1);
}

// Exclusive scan of deg -> row_ptr; also dinv[i] = rsqrt(deg[i]+1) (self-loop).
// Single block of 1024 threads, Hillis-Steele per chunk with running carry.
__global__ void k_scan(const int* __restrict__ deg, int* __restrict__ row_ptr,
                       float* __restrict__ dinv, int n) {
    __shared__ int sdata[1024];
    int carry = 0;
    for (int base = 0; base < n; base += 1024) {
        int i = base + (int)threadIdx.x;
        int v = (i < n) ? deg[i] : 0;
        if (i < n) dinv[i] = rsqrtf((float)(v + 1));
        sdata[threadIdx.x] = v;
        __syncthreads();
        for (int off = 1; off < 1024; off <<= 1) {
            int t = (threadIdx.x >= (unsigned)off) ? sdata[threadIdx.x - off] : 0;
            __syncthreads();
            sdata[threadIdx.x] += t;
            __syncthreads();
        }
        if (i < n) row_ptr[i] = carry + sdata[threadIdx.x] - v;  // exclusive
        carry += sdata[1023];
        __syncthreads();
    }
    if (threadIdx.x == 0) row_ptr[n] = carry;
}

__global__ void k_fill(const int* __restrict__ src, const int* __restrict__ dst,
                       const int* __restrict__ row_ptr, int* __restrict__ row_cur,
                       int* __restrict__ col_src, int e) {
    int i = blockIdx.x * blockDim.x + threadIdx.x;
    if (i < e) {
        int d = dst[i];
        int pos = row_ptr[d] + atomicAdd(&row_cur[d], 1);
        col_src[pos] = src[i];
    }
}

// ---------------------------------------------------------------------------
// GEMM + dinv-scale epilogue: out[r] = dinv[r] * (A[r] @ W)   [n x 128]
// Block = 256 threads, 32 rows/block; each thread computes a 4x4 tile.
// FMA:ds_read = 16:4 per k -> VALU-bound.
// ---------------------------------------------------------------------------
__global__ __launch_bounds__(256) void k_gemm_scaled(
        const float* __restrict__ A, const float* __restrict__ W,
        const float* __restrict__ dinv, float* __restrict__ out, int n) {
    __shared__ float As[32][FDIM];   // 16 KB
    int tid = threadIdx.x;
    int r0 = blockIdx.x * 32;
    // stage A-tile: 32 rows x 32 float4
    for (int t = tid; t < 32 * 32; t += 256) {
        int r = t >> 5, c4 = t & 31;
        int gr = r0 + r;
        float4 v = make_float4(0.f, 0.f, 0.f, 0.f);
        if (gr < n) v = ((const float4*)A)[(size_t)gr * 32 + c4];
        ((float4*)As[r])[c4] = v;
    }
    __syncthreads();
    int cb = (tid & 31) * 4;   // column base (float4)
    int rb = (tid >> 5) * 4;   // row base
    float4 acc0 = make_float4(0,0,0,0), acc1 = acc0, acc2 = acc0, acc3 = acc0;
    for (int k = 0; k < FDIM; ++k) {
        float4 w = *(const float4*)(W + k * FDIM + cb);
        float a0 = As[rb + 0][k], a1 = As[rb + 1][k];
        float a2 = As[rb + 2][k], a3 = As[rb + 3][k];
        acc0.x += a0 * w.x; acc0.y += a0 * w.y; acc0.z += a0 * w.z; acc0.w += a0 * w.w;
        acc1.x += a1 * w.x; acc1.y += a1 * w.y; acc1.z += a1 * w.z; acc1.w += a1 * w.w;
        acc2.x += a2 * w.x; acc2.y += a2 * w.y; acc2.z += a2 * w.z; acc2.w += a2 * w.w;
        acc3.x += a3 * w.x; acc3.y += a3 * w.y; acc3.z += a3 * w.z; acc3.w += a3 * w.w;
    }
    float4 accs[4] = {acc0, acc1, acc2, acc3};
    for (int i = 0; i < 4; ++i) {
        int gr = r0 + rb + i;
        if (gr < n) {
            float s = dinv[gr];
            float4 v = accs[i];
            v.x *= s; v.y *= s; v.z *= s; v.w *= s;
            ((float4*)out)[(size_t)gr * 32 + (cb >> 2)] = v;
        }
    }
}

// ---------------------------------------------------------------------------
// Aggregation over pre-scaled rows hs[r] = dinv[r]*h[r]:
//   out[i] = maybe_relu( dinv[i] * (sum_{s in N(i)} hs[s] + hs[i]) + bias )
// 32 lanes per node (float4/lane), 8 nodes/block, neighbor loop unrolled x4
// -> 4 independent 512B gathers in flight per group.
// ---------------------------------------------------------------------------
template <bool RELU>
__global__ __launch_bounds__(256) void k_agg(
        const float4* __restrict__ hs4, const float* __restrict__ dinv,
        const int* __restrict__ row_ptr, const int* __restrict__ col_src,
        const float4* __restrict__ bias4, float4* __restrict__ out4, int n) {
    int node = blockIdx.x * 8 + (int)(threadIdx.x >> 5);
    int lane = threadIdx.x & 31;
    if (node >= n) return;
    int beg = row_ptr[node];
    int end = row_ptr[node + 1];
    float4 acc = hs4[node * 32 + lane];   // self-loop term
    int j = beg;
    for (; j + 4 <= end; j += 4) {
        int s0 = col_src[j + 0], s1 = col_src[j + 1];
        int s2 = col_src[j + 2], s3 = col_src[j + 3];
        float4 a0 = hs4[(size_t)s0 * 32 + lane];
        float4 a1 = hs4[(size_t)s1 * 32 + lane];
        float4 a2 = hs4[(size_t)s2 * 32 + lane];
        float4 a3 = hs4[(size_t)s3 * 32 + lane];
        acc.x += (a0.x + a1.x) + (a2.x + a3.x);
        acc.y += (a0.y + a1.y) + (a2.y + a3.y);
        acc.z += (a0.z + a1.z) + (a2.z + a3.z);
        acc.w += (a0.w + a1.w) + (a2.w + a3.w);
    }
    for (; j < end; ++j) {
        float4 a = hs4[(size_t)col_src[j] * 32 + lane];
        acc.x += a.x; acc.y += a.y; acc.z += a.z; acc.w += a.w;
    }
    float di = dinv[node];
    float4 b = bias4[lane];
    float4 v;
    v.x = di * acc.x + b.x; v.y = di * acc.y + b.y;
    v.z = di * acc.z + b.z; v.w = di * acc.w + b.w;
    if (RELU) {
        v.x = fmaxf(v.x, 0.f); v.y = fmaxf(v.y, 0.f);
        v.z = fmaxf(v.z, 0.f); v.w = fmaxf(v.w, 0.f);
    }
    out4[node * 32 + lane] = v;
}

// ---------------------------------------------------------------------------
// Classifier + log_softmax: one 64-lane wave per node, lane c < 40 computes
// logit c; k-loop unrolled x4 with float4 broadcast of the h-row.
// ---------------------------------------------------------------------------
__global__ void k_cls(const float* __restrict__ h, const float* __restrict__ Wc,
                      const float* __restrict__ bc, float* __restrict__ out, int n) {
    int node = blockIdx.x * 4 + (int)(threadIdx.x >> 6);
    int lane = threadIdx.x & 63;
    if (node >= n) return;
    const float4* hrow4 = (const float4*)(h + (size_t)node * FDIM);
    float acc = 0.0f;
    if (lane < CDIM) {
        acc = bc[lane];
        for (int k4 = 0; k4 < FDIM / 4; ++k4) {
            float4 h4 = hrow4[k4];
            int k = k4 * 4;
            acc += h4.x * Wc[(k + 0) * CDIM + lane];
            acc += h4.y * Wc[(k + 1) * CDIM + lane];
            acc += h4.z * Wc[(k + 2) * CDIM + lane];
            acc += h4.w * Wc[(k + 3) * CDIM + lane];
        }
    }
    float v = (lane < CDIM) ? acc : -INFINITY;
    float m = v;
    for (int off = 32; off > 0; off >>= 1) m = fmaxf(m, __shfl_down(m, off));
    m = __shfl(m, 0);
    float e = (lane < CDIM) ? expf(v - m) : 0.0f;
    float s = e;
    for (int off = 32; off > 0; off >>= 1) s += __shfl_down(s, off);
    s = __shfl(s, 0);
    if (lane < CDIM) out[(size_t)node * CDIM + lane] = v - m - logf(s);
}

// ---------------------------------------------------------------------------

extern "C" void kernel_launch(void* const* d_in, const int* in_sizes, int n_in,
                              void* d_out, int out_size, void* d_ws, size_t ws_size,
                              hipStream_t stream) {
    const float* x  = (const float*)d_in[0];
    const int*   ei = (const int*)d_in[1];
    const float* W1 = (const float*)d_in[2];
    const float* b1 = (const float*)d_in[3];
    const float* W2 = (const float*)d_in[4];
    const float* b2 = (const float*)d_in[5];
    const float* Wc = (const float*)d_in[6];
    const float* bc = (const float*)d_in[7];
    float* out = (float*)d_out;

    const int N = in_sizes[0] / FDIM;
    const int E = in_sizes[1] / 2;
    const int* srcp = ei;         // edge_index[0]
    const int* dstp = ei + E;     // edge_index[1]

    char* ws = (char*)d_ws;
    auto alloc = [&](size_t bytes) {
        char* p = ws;
        ws += (bytes + 255) & ~(size_t)255;
        return p;
    };
    int*   deg     = (int*)  alloc((size_t)N * 4);
    int*   row_cur = (int*)  alloc((size_t)N * 4);
    int*   row_ptr = (int*)  alloc((size_t)(N + 1) * 4);
    float* dinv    = (float*)alloc((size_t)N * 4);
    int*   col_src = (int*)  alloc((size_t)E * 4);
    float* hbuf    = (float*)alloc((size_t)N * FDIM * 4);
    float* aggbuf  = (float*)alloc((size_t)N * FDIM * 4);

    // Graph build
    k_init <<<(N + 255) / 256, 256, 0, stream>>>(deg, row_cur, N);
    k_count<<<(E + 255) / 256, 256, 0, stream>>>(dstp, deg, E);
    k_scan <<<1, 1024, 0, stream>>>(deg, row_ptr, dinv, N);
    k_fill <<<(E + 255) / 256, 256, 0, stream>>>(srcp, dstp, row_ptr, row_cur, col_src, E);

    // Layer 1: hs = dinv*(x@W1) ; agg(+b1, relu)
    k_gemm_scaled<<<(N + 31) / 32, 256, 0, stream>>>(x, W1, dinv, hbuf, N);
    k_agg<true><<<(N + 7) / 8, 256, 0, stream>>>(
        (const float4*)hbuf, dinv, row_ptr, col_src, (const float4*)b1,
        (float4*)aggbuf, N);

    // Layer 2: hs = dinv*(agg@W2) ; agg(+b2)
    k_gemm_scaled<<<(N + 31) / 32, 256, 0, stream>>>(aggbuf, W2, dinv, hbuf, N);
    k_agg<false><<<(N + 7) / 8, 256, 0, stream>>>(
        (const float4*)hbuf, dinv, row_ptr, col_src, (const float4*)b2,
        (float4*)aggbuf, N);

    // Classifier + log_softmax
    k_cls<<<(N + 3) / 4, 256, 0, stream>>>(aggbuf, Wc, bc, out, N);
}

// Round 3
// 233.072 us; speedup vs baseline: 1.8608x; 1.1722x over previous
//
#include <hip/hip_runtime.h>
#include <math.h>

#define FDIM 128
#define CDIM 40

// ---------------------------------------------------------------------------
// Graph preprocessing
// ---------------------------------------------------------------------------

__global__ void k_init(int* __restrict__ deg, int n) {
    int i = blockIdx.x * blockDim.x + threadIdx.x;
    if (i < n) deg[i] = 0;
}

// Count degrees; the atomic's return value is this edge's rank within its dst
// (saved coalesced) so the fill pass needs no atomics.
__global__ void k_count(const int* __restrict__ dst, int* __restrict__ deg,
                        int* __restrict__ pos_within, int e) {
    int i = blockIdx.x * blockDim.x + threadIdx.x;
    if (i < e) {
        int d = dst[i];
        pos_within[i] = atomicAdd(&deg[d], 1);
    }
}

// Single-block exclusive scan (n <= 16384): 16 items/thread serial prefix,
// wave shuffle-scan, cross-wave LDS combine. Also emits dinv = rsqrt(deg+1).
__global__ __launch_bounds__(1024) void k_scan(const int* __restrict__ deg,
                                               int* __restrict__ row_ptr,
                                               float* __restrict__ dinv, int n) {
    int tid = threadIdx.x;
    int base = tid * 16;
    int vals[16];
    int sum = 0;
    #pragma unroll
    for (int k = 0; k < 16; ++k) {
        int i = base + k;
        int v = (i < n) ? deg[i] : 0;
        vals[k] = sum;              // thread-local exclusive prefix
        sum += v;
        if (i < n) dinv[i] = rsqrtf((float)(v + 1));
    }
    int lane = tid & 63;
    int wave = tid >> 6;
    int x = sum;                    // wave inclusive scan
    #pragma unroll
    for (int off = 1; off < 64; off <<= 1) {
        int y = __shfl_up(x, off);
        if (lane >= off) x += y;
    }
    __shared__ int wsum[16];
    if (lane == 63) wsum[wave] = x;
    __syncthreads();
    if (wave == 0) {
        int w = (lane < 16) ? wsum[lane] : 0;
        #pragma unroll
        for (int off = 1; off < 16; off <<= 1) {
            int y = __shfl_up(w, off);
            if (lane >= off) w += y;
        }
        if (lane < 16) wsum[lane] = w;   // inclusive wave totals
    }
    __syncthreads();
    int wave_off = (wave > 0) ? wsum[wave - 1] : 0;
    int thread_excl = wave_off + x - sum;
    #pragma unroll
    for (int k = 0; k < 16; ++k) {
        int i = base + k;
        if (i < n) row_ptr[i] = thread_excl + vals[k];
    }
    if (tid == 1023) row_ptr[n] = wave_off + x;   // grand total
}

// ---------------------------------------------------------------------------
// Mega kernel: blocks [0, gemm_blocks) run layer-1 GEMM (+dinv scale);
// blocks [gemm_blocks, ...) run the CSR fill (atomic-free scatter).
// The fill's latency stalls overlap with the GEMM's VALU work.
// ---------------------------------------------------------------------------
__global__ __launch_bounds__(256) void k_mega(
        const float* __restrict__ A, const float* __restrict__ W,
        const float* __restrict__ dinv, float* __restrict__ out, int n,
        const int* __restrict__ src, const int* __restrict__ dst,
        const int* __restrict__ row_ptr, const int* __restrict__ pos_within,
        int* __restrict__ col_src, int e, int gemm_blocks) {
    __shared__ float As[32][FDIM];   // used by gemm path only (16 KB)
    int tid = threadIdx.x;
    if ((int)blockIdx.x < gemm_blocks) {
        int r0 = blockIdx.x * 32;
        for (int t = tid; t < 32 * 32; t += 256) {
            int r = t >> 5, c4 = t & 31;
            int gr = r0 + r;
            float4 v = make_float4(0.f, 0.f, 0.f, 0.f);
            if (gr < n) v = ((const float4*)A)[(size_t)gr * 32 + c4];
            ((float4*)As[r])[c4] = v;
        }
        __syncthreads();
        int cb = (tid & 31) * 4;
        int rb = (tid >> 5) * 4;
        float4 acc0 = make_float4(0,0,0,0), acc1 = acc0, acc2 = acc0, acc3 = acc0;
        for (int k = 0; k < FDIM; ++k) {
            float4 w = *(const float4*)(W + k * FDIM + cb);
            float a0 = As[rb + 0][k], a1 = As[rb + 1][k];
            float a2 = As[rb + 2][k], a3 = As[rb + 3][k];
            acc0.x += a0 * w.x; acc0.y += a0 * w.y; acc0.z += a0 * w.z; acc0.w += a0 * w.w;
            acc1.x += a1 * w.x; acc1.y += a1 * w.y; acc1.z += a1 * w.z; acc1.w += a1 * w.w;
            acc2.x += a2 * w.x; acc2.y += a2 * w.y; acc2.z += a2 * w.z; acc2.w += a2 * w.w;
            acc3.x += a3 * w.x; acc3.y += a3 * w.y; acc3.z += a3 * w.z; acc3.w += a3 * w.w;
        }
        float4 accs[4] = {acc0, acc1, acc2, acc3};
        for (int i = 0; i < 4; ++i) {
            int gr = r0 + rb + i;
            if (gr < n) {
                float s = dinv[gr];
                float4 v = accs[i];
                v.x *= s; v.y *= s; v.z *= s; v.w *= s;
                ((float4*)out)[(size_t)gr * 32 + (cb >> 2)] = v;
            }
        }
    } else {
        int i = ((int)blockIdx.x - gemm_blocks) * 256 + tid;
        if (i < e) {
            int d = dst[i];
            col_src[row_ptr[d] + pos_within[i]] = src[i];
        }
    }
}

// Standalone GEMM (+dinv scale) for layer 2.
__global__ __launch_bounds__(256) void k_gemm_scaled(
        const float* __restrict__ A, const float* __restrict__ W,
        const float* __restrict__ dinv, float* __restrict__ out, int n) {
    __shared__ float As[32][FDIM];
    int tid = threadIdx.x;
    int r0 = blockIdx.x * 32;
    for (int t = tid; t < 32 * 32; t += 256) {
        int r = t >> 5, c4 = t & 31;
        int gr = r0 + r;
        float4 v = make_float4(0.f, 0.f, 0.f, 0.f);
        if (gr < n) v = ((const float4*)A)[(size_t)gr * 32 + c4];
        ((float4*)As[r])[c4] = v;
    }
    __syncthreads();
    int cb = (tid & 31) * 4;
    int rb = (tid >> 5) * 4;
    float4 acc0 = make_float4(0,0,0,0), acc1 = acc0, acc2 = acc0, acc3 = acc0;
    for (int k = 0; k < FDIM; ++k) {
        float4 w = *(const float4*)(W + k * FDIM + cb);
        float a0 = As[rb + 0][k], a1 = As[rb + 1][k];
        float a2 = As[rb + 2][k], a3 = As[rb + 3][k];
        acc0.x += a0 * w.x; acc0.y += a0 * w.y; acc0.z += a0 * w.z; acc0.w += a0 * w.w;
        acc1.x += a1 * w.x; acc1.y += a1 * w.y; acc1.z += a1 * w.z; acc1.w += a1 * w.w;
        acc2.x += a2 * w.x; acc2.y += a2 * w.y; acc2.z += a2 * w.z; acc2.w += a2 * w.w;
        acc3.x += a3 * w.x; acc3.y += a3 * w.y; acc3.z += a3 * w.z; acc3.w += a3 * w.w;
    }
    float4 accs[4] = {acc0, acc1, acc2, acc3};
    for (int i = 0; i < 4; ++i) {
        int gr = r0 + rb + i;
        if (gr < n) {
            float s = dinv[gr];
            float4 v = accs[i];
            v.x *= s; v.y *= s; v.z *= s; v.w *= s;
            ((float4*)out)[(size_t)gr * 32 + (cb >> 2)] = v;
        }
    }
}

// ---------------------------------------------------------------------------
// Aggregation over pre-scaled rows hs[r] = dinv[r]*h[r]:
//   out[i] = maybe_relu( dinv[i] * (sum_{s in N(i)} hs[s] + hs[i]) + bias )
// 32 lanes/node (float4), 8 nodes/block, unroll x8 with split accumulators
// -> 8 independent 512B gathers in flight per group.
// ---------------------------------------------------------------------------
template <bool RELU>
__global__ __launch_bounds__(256) void k_agg(
        const float4* __restrict__ hs4, const float* __restrict__ dinv,
        const int* __restrict__ row_ptr, const int* __restrict__ col_src,
        const float4* __restrict__ bias4, float4* __restrict__ out4, int n) {
    int node = blockIdx.x * 8 + (int)(threadIdx.x >> 5);
    int lane = threadIdx.x & 31;
    if (node >= n) return;
    int beg = row_ptr[node];
    int end = row_ptr[node + 1];
    float4 acc0 = hs4[node * 32 + lane];   // self-loop term
    float4 acc1 = make_float4(0.f, 0.f, 0.f, 0.f);
    int j = beg;
    for (; j + 8 <= end; j += 8) {
        int s0 = col_src[j + 0], s1 = col_src[j + 1];
        int s2 = col_src[j + 2], s3 = col_src[j + 3];
        int s4 = col_src[j + 4], s5 = col_src[j + 5];
        int s6 = col_src[j + 6], s7 = col_src[j + 7];
        float4 a0 = hs4[(size_t)s0 * 32 + lane];
        float4 a1 = hs4[(size_t)s1 * 32 + lane];
        float4 a2 = hs4[(size_t)s2 * 32 + lane];
        float4 a3 = hs4[(size_t)s3 * 32 + lane];
        float4 a4 = hs4[(size_t)s4 * 32 + lane];
        float4 a5 = hs4[(size_t)s5 * 32 + lane];
        float4 a6 = hs4[(size_t)s6 * 32 + lane];
        float4 a7 = hs4[(size_t)s7 * 32 + lane];
        acc0.x += (a0.x + a2.x) + (a4.x + a6.x);
        acc0.y += (a0.y + a2.y) + (a4.y + a6.y);
        acc0.z += (a0.z + a2.z) + (a4.z + a6.z);
        acc0.w += (a0.w + a2.w) + (a4.w + a6.w);
        acc1.x += (a1.x + a3.x) + (a5.x + a7.x);
        acc1.y += (a1.y + a3.y) + (a5.y + a7.y);
        acc1.z += (a1.z + a3.z) + (a5.z + a7.z);
        acc1.w += (a1.w + a3.w) + (a5.w + a7.w);
    }
    for (; j < end; ++j) {
        float4 a = hs4[(size_t)col_src[j] * 32 + lane];
        acc0.x += a.x; acc0.y += a.y; acc0.z += a.z; acc0.w += a.w;
    }
    float di = dinv[node];
    float4 b = bias4[lane];
    float4 v;
    v.x = di * (acc0.x + acc1.x) + b.x;
    v.y = di * (acc0.y + acc1.y) + b.y;
    v.z = di * (acc0.z + acc1.z) + b.z;
    v.w = di * (acc0.w + acc1.w) + b.w;
    if (RELU) {
        v.x = fmaxf(v.x, 0.f); v.y = fmaxf(v.y, 0.f);
        v.z = fmaxf(v.z, 0.f); v.w = fmaxf(v.w, 0.f);
    }
    out4[node * 32 + lane] = v;
}

// ---------------------------------------------------------------------------
// Classifier + log_softmax: one 64-lane wave per node.
// ---------------------------------------------------------------------------
__global__ void k_cls(const float* __restrict__ h, const float* __restrict__ Wc,
                      const float* __restrict__ bc, float* __restrict__ out, int n) {
    int node = blockIdx.x * 4 + (int)(threadIdx.x >> 6);
    int lane = threadIdx.x & 63;
    if (node >= n) return;
    const float4* hrow4 = (const float4*)(h + (size_t)node * FDIM);
    float acc = 0.0f;
    if (lane < CDIM) {
        acc = bc[lane];
        for (int k4 = 0; k4 < FDIM / 4; ++k4) {
            float4 h4 = hrow4[k4];
            int k = k4 * 4;
            acc += h4.x * Wc[(k + 0) * CDIM + lane];
            acc += h4.y * Wc[(k + 1) * CDIM + lane];
            acc += h4.z * Wc[(k + 2) * CDIM + lane];
            acc += h4.w * Wc[(k + 3) * CDIM + lane];
        }
    }
    float v = (lane < CDIM) ? acc : -INFINITY;
    float m = v;
    for (int off = 32; off > 0; off >>= 1) m = fmaxf(m, __shfl_down(m, off));
    m = __shfl(m, 0);
    float e = (lane < CDIM) ? expf(v - m) : 0.0f;
    float s = e;
    for (int off = 32; off > 0; off >>= 1) s += __shfl_down(s, off);
    s = __shfl(s, 0);
    if (lane < CDIM) out[(size_t)node * CDIM + lane] = v - m - logf(s);
}

// ---------------------------------------------------------------------------

extern "C" void kernel_launch(void* const* d_in, const int* in_sizes, int n_in,
                              void* d_out, int out_size, void* d_ws, size_t ws_size,
                              hipStream_t stream) {
    const float* x  = (const float*)d_in[0];
    const int*   ei = (const int*)d_in[1];
    const float* W1 = (const float*)d_in[2];
    const float* b1 = (const float*)d_in[3];
    const float* W2 = (const float*)d_in[4];
    const float* b2 = (const float*)d_in[5];
    const float* Wc = (const float*)d_in[6];
    const float* bc = (const float*)d_in[7];
    float* out = (float*)d_out;

    const int N = in_sizes[0] / FDIM;
    const int E = in_sizes[1] / 2;
    const int* srcp = ei;         // edge_index[0]
    const int* dstp = ei + E;     // edge_index[1]

    char* ws = (char*)d_ws;
    auto alloc = [&](size_t bytes) {
        char* p = ws;
        ws += (bytes + 255) & ~(size_t)255;
        return p;
    };
    int*   deg        = (int*)  alloc((size_t)N * 4);
    int*   row_ptr    = (int*)  alloc((size_t)(N + 1) * 4);
    float* dinv       = (float*)alloc((size_t)N * 4);
    int*   pos_within = (int*)  alloc((size_t)E * 4);
    int*   col_src    = (int*)  alloc((size_t)E * 4);
    float* hbuf       = (float*)alloc((size_t)N * FDIM * 4);
    float* aggbuf     = (float*)alloc((size_t)N * FDIM * 4);

    // Graph build (count saves per-edge rank -> atomic-free fill later)
    k_init <<<(N + 255) / 256, 256, 0, stream>>>(deg, N);
    k_count<<<(E + 255) / 256, 256, 0, stream>>>(dstp, deg, pos_within, E);
    k_scan <<<1, 1024, 0, stream>>>(deg, row_ptr, dinv, N);

    // Layer-1 GEMM fused with CSR fill (independent work, one dispatch)
    int gemm_blocks = (N + 31) / 32;
    int fill_blocks = (E + 255) / 256;
    k_mega<<<gemm_blocks + fill_blocks, 256, 0, stream>>>(
        x, W1, dinv, hbuf, N, srcp, dstp, row_ptr, pos_within, col_src, E,
        gemm_blocks);

    k_agg<true><<<(N + 7) / 8, 256, 0, stream>>>(
        (const float4*)hbuf, dinv, row_ptr, col_src, (const float4*)b1,
        (float4*)aggbuf, N);

    // Layer 2
    k_gemm_scaled<<<(N + 31) / 32, 256, 0, stream>>>(aggbuf, W2, dinv, hbuf, N);
    k_agg<false><<<(N + 7) / 8, 256, 0, stream>>>(
        (const float4*)hbuf, dinv, row_ptr, col_src, (const float4*)b2,
        (float4*)aggbuf, N);

    // Classifier + log_softmax
    k_cls<<<(N + 3) / 4, 256, 0, stream>>>(aggbuf, Wc, bc, out, N);
}

// Round 4
// 225.393 us; speedup vs baseline: 1.9242x; 1.0341x over previous
//
#include <hip/hip_runtime.h>
#include <math.h>

#define FDIM 128
#define CDIM 40

// ---------------------------------------------------------------------------
// Graph preprocessing
// ---------------------------------------------------------------------------

__global__ void k_init(int* __restrict__ deg, int n) {
    int i = blockIdx.x * blockDim.x + threadIdx.x;
    if (i < n) deg[i] = 0;
}

// Count degrees, 4 edges/thread (int4). The atomic's return value is each
// edge's rank within its dst (coalesced store) -> atomic-free fill later.
__global__ void k_count(const int* __restrict__ dst, int* __restrict__ deg,
                        int* __restrict__ pos_within, int e) {
    int i = blockIdx.x * blockDim.x + threadIdx.x;
    int i4 = i * 4;
    if (i4 + 3 < e) {
        int4 d = ((const int4*)dst)[i];
        int4 p;
        p.x = atomicAdd(&deg[d.x], 1);
        p.y = atomicAdd(&deg[d.y], 1);
        p.z = atomicAdd(&deg[d.z], 1);
        p.w = atomicAdd(&deg[d.w], 1);
        ((int4*)pos_within)[i] = p;
    } else if (i4 < e) {
        for (int k = i4; k < e; ++k)
            pos_within[k] = atomicAdd(&deg[dst[k]], 1);
    }
}

// Single-block exclusive scan (n <= 16384): 16 items/thread serial prefix,
// wave shuffle-scan, cross-wave LDS combine. Also emits dinv = rsqrt(deg+1).
__global__ __launch_bounds__(1024) void k_scan(const int* __restrict__ deg,
                                               int* __restrict__ row_ptr,
                                               float* __restrict__ dinv, int n) {
    int tid = threadIdx.x;
    int base = tid * 16;
    int vals[16];
    int sum = 0;
    #pragma unroll
    for (int k = 0; k < 16; ++k) {
        int i = base + k;
        int v = (i < n) ? deg[i] : 0;
        vals[k] = sum;
        sum += v;
        if (i < n) dinv[i] = rsqrtf((float)(v + 1));
    }
    int lane = tid & 63;
    int wave = tid >> 6;
    int x = sum;
    #pragma unroll
    for (int off = 1; off < 64; off <<= 1) {
        int y = __shfl_up(x, off);
        if (lane >= off) x += y;
    }
    __shared__ int wsum[16];
    if (lane == 63) wsum[wave] = x;
    __syncthreads();
    if (wave == 0) {
        int w = (lane < 16) ? wsum[lane] : 0;
        #pragma unroll
        for (int off = 1; off < 16; off <<= 1) {
            int y = __shfl_up(w, off);
            if (lane >= off) w += y;
        }
        if (lane < 16) wsum[lane] = w;
    }
    __syncthreads();
    int wave_off = (wave > 0) ? wsum[wave - 1] : 0;
    int thread_excl = wave_off + x - sum;
    #pragma unroll
    for (int k = 0; k < 16; ++k) {
        int i = base + k;
        if (i < n) row_ptr[i] = thread_excl + vals[k];
    }
    if (tid == 1023) row_ptr[n] = wave_off + x;
}

// ---------------------------------------------------------------------------
// Mega kernel: blocks [0, gemm_blocks) = layer-1 GEMM (out = dinv*(A@W));
// remaining blocks = atomic-free CSR fill, 4 edges/thread.
// ---------------------------------------------------------------------------
__global__ __launch_bounds__(256) void k_mega(
        const float* __restrict__ A, const float* __restrict__ W,
        const float* __restrict__ dinv, float* __restrict__ out, int n,
        const int* __restrict__ src, const int* __restrict__ dst,
        const int* __restrict__ row_ptr, const int* __restrict__ pos_within,
        int* __restrict__ col_src, int e, int gemm_blocks) {
    __shared__ float As[32][FDIM];
    int tid = threadIdx.x;
    if ((int)blockIdx.x < gemm_blocks) {
        int r0 = blockIdx.x * 32;
        for (int t = tid; t < 32 * 32; t += 256) {
            int r = t >> 5, c4 = t & 31;
            int gr = r0 + r;
            float4 v = make_float4(0.f, 0.f, 0.f, 0.f);
            if (gr < n) v = ((const float4*)A)[(size_t)gr * 32 + c4];
            ((float4*)As[r])[c4] = v;
        }
        __syncthreads();
        int cb = (tid & 31) * 4;
        int rb = (tid >> 5) * 4;
        float4 acc0 = make_float4(0,0,0,0), acc1 = acc0, acc2 = acc0, acc3 = acc0;
        for (int k = 0; k < FDIM; ++k) {
            float4 w = *(const float4*)(W + k * FDIM + cb);
            float a0 = As[rb + 0][k], a1 = As[rb + 1][k];
            float a2 = As[rb + 2][k], a3 = As[rb + 3][k];
            acc0.x += a0 * w.x; acc0.y += a0 * w.y; acc0.z += a0 * w.z; acc0.w += a0 * w.w;
            acc1.x += a1 * w.x; acc1.y += a1 * w.y; acc1.z += a1 * w.z; acc1.w += a1 * w.w;
            acc2.x += a2 * w.x; acc2.y += a2 * w.y; acc2.z += a2 * w.z; acc2.w += a2 * w.w;
            acc3.x += a3 * w.x; acc3.y += a3 * w.y; acc3.z += a3 * w.z; acc3.w += a3 * w.w;
        }
        float4 accs[4] = {acc0, acc1, acc2, acc3};
        for (int i = 0; i < 4; ++i) {
            int gr = r0 + rb + i;
            if (gr < n) {
                float s = dinv[gr];
                float4 v = accs[i];
                v.x *= s; v.y *= s; v.z *= s; v.w *= s;
                ((float4*)out)[(size_t)gr * 32 + (cb >> 2)] = v;
            }
        }
    } else {
        int i = ((int)blockIdx.x - gemm_blocks) * 256 + tid;
        int i4 = i * 4;
        if (i4 + 3 < e) {
            int4 d = ((const int4*)dst)[i];
            int4 s = ((const int4*)src)[i];
            int4 p = ((const int4*)pos_within)[i];
            col_src[row_ptr[d.x] + p.x] = s.x;
            col_src[row_ptr[d.y] + p.y] = s.y;
            col_src[row_ptr[d.z] + p.z] = s.z;
            col_src[row_ptr[d.w] + p.w] = s.w;
        } else if (i4 < e) {
            for (int k = i4; k < e; ++k)
                col_src[row_ptr[dst[k]] + pos_within[k]] = src[k];
        }
    }
}

// ---------------------------------------------------------------------------
// Aggregate-16-rows-into-LDS phase, shared by the two fused kernels.
// 8 groups x 32 lanes; group g does local rows g and g+8. Unroll x8 gathers.
// ---------------------------------------------------------------------------
template <bool RELU>
__device__ __forceinline__ void agg_to_lds(
        float (*As)[FDIM], const float4* __restrict__ hs4,
        const float* __restrict__ dinv, const int* __restrict__ row_ptr,
        const int* __restrict__ col_src, const float4* __restrict__ bias4,
        int r0, int n, int tid) {
    int g = tid >> 5, lane = tid & 31;
    #pragma unroll
    for (int ii = 0; ii < 2; ++ii) {
        int li = g + 8 * ii;
        int node = r0 + li;
        float4 v = make_float4(0.f, 0.f, 0.f, 0.f);
        if (node < n) {
            int beg = row_ptr[node], end = row_ptr[node + 1];
            float4 acc0 = hs4[(size_t)node * 32 + lane];   // self-loop
            float4 acc1 = make_float4(0.f, 0.f, 0.f, 0.f);
            int j = beg;
            for (; j + 8 <= end; j += 8) {
                int s0 = col_src[j + 0], s1 = col_src[j + 1];
                int s2 = col_src[j + 2], s3 = col_src[j + 3];
                int s4 = col_src[j + 4], s5 = col_src[j + 5];
                int s6 = col_src[j + 6], s7 = col_src[j + 7];
                float4 a0 = hs4[(size_t)s0 * 32 + lane];
                float4 a1 = hs4[(size_t)s1 * 32 + lane];
                float4 a2 = hs4[(size_t)s2 * 32 + lane];
                float4 a3 = hs4[(size_t)s3 * 32 + lane];
                float4 a4 = hs4[(size_t)s4 * 32 + lane];
                float4 a5 = hs4[(size_t)s5 * 32 + lane];
                float4 a6 = hs4[(size_t)s6 * 32 + lane];
                float4 a7 = hs4[(size_t)s7 * 32 + lane];
                acc0.x += (a0.x + a2.x) + (a4.x + a6.x);
                acc0.y += (a0.y + a2.y) + (a4.y + a6.y);
                acc0.z += (a0.z + a2.z) + (a4.z + a6.z);
                acc0.w += (a0.w + a2.w) + (a4.w + a6.w);
                acc1.x += (a1.x + a3.x) + (a5.x + a7.x);
                acc1.y += (a1.y + a3.y) + (a5.y + a7.y);
                acc1.z += (a1.z + a3.z) + (a5.z + a7.z);
                acc1.w += (a1.w + a3.w) + (a5.w + a7.w);
            }
            for (; j < end; ++j) {
                float4 a = hs4[(size_t)col_src[j] * 32 + lane];
                acc0.x += a.x; acc0.y += a.y; acc0.z += a.z; acc0.w += a.w;
            }
            float di = dinv[node];
            float4 b = bias4[lane];
            v.x = di * (acc0.x + acc1.x) + b.x;
            v.y = di * (acc0.y + acc1.y) + b.y;
            v.z = di * (acc0.z + acc1.z) + b.z;
            v.w = di * (acc0.w + acc1.w) + b.w;
            if (RELU) {
                v.x = fmaxf(v.x, 0.f); v.y = fmaxf(v.y, 0.f);
                v.z = fmaxf(v.z, 0.f); v.w = fmaxf(v.w, 0.f);
            }
        }
        ((float4*)As[li])[lane] = v;
    }
}

// ---------------------------------------------------------------------------
// Fused: agg1(+b1, ReLU) -> @W2 -> dinv scale -> out (hs2). 16 rows/block.
// ---------------------------------------------------------------------------
__global__ __launch_bounds__(256) void k_agg_gemm(
        const float4* __restrict__ hs4, const float* __restrict__ dinv,
        const int* __restrict__ row_ptr, const int* __restrict__ col_src,
        const float4* __restrict__ bias4, const float* __restrict__ W2,
        float* __restrict__ out, int n) {
    __shared__ float As[16][FDIM];   // 8 KB
    int tid = threadIdx.x;
    int r0 = blockIdx.x * 16;
    agg_to_lds<true>(As, hs4, dinv, row_ptr, col_src, bias4, r0, n, tid);
    __syncthreads();
    int cb = (tid & 31) * 4;
    int rb = (tid >> 5) * 2;
    float4 acc0 = make_float4(0,0,0,0), acc1 = acc0;
    for (int k = 0; k < FDIM; ++k) {
        float4 w = *(const float4*)(W2 + k * FDIM + cb);
        float a0 = As[rb + 0][k], a1 = As[rb + 1][k];
        acc0.x += a0 * w.x; acc0.y += a0 * w.y; acc0.z += a0 * w.z; acc0.w += a0 * w.w;
        acc1.x += a1 * w.x; acc1.y += a1 * w.y; acc1.z += a1 * w.z; acc1.w += a1 * w.w;
    }
    float4 accs[2] = {acc0, acc1};
    #pragma unroll
    for (int i = 0; i < 2; ++i) {
        int gr = r0 + rb + i;
        if (gr < n) {
            float s = dinv[gr];
            float4 v = accs[i];
            v.x *= s; v.y *= s; v.z *= s; v.w *= s;
            ((float4*)out)[(size_t)gr * 32 + (cb >> 2)] = v;
        }
    }
}

// ---------------------------------------------------------------------------
// Fused: agg2(+b2) -> classifier (@Wc + bc) -> log_softmax -> out.
// 16 rows/block; phase B: 4 waves x 4 nodes, lane c<40 computes logit c.
// ---------------------------------------------------------------------------
__global__ __launch_bounds__(256) void k_agg_cls(
        const float4* __restrict__ hs4, const float* __restrict__ dinv,
        const int* __restrict__ row_ptr, const int* __restrict__ col_src,
        const float4* __restrict__ bias4, const float* __restrict__ Wc,
        const float* __restrict__ bc, float* __restrict__ out, int n) {
    __shared__ float As[16][FDIM];   // 8 KB
    int tid = threadIdx.x;
    int r0 = blockIdx.x * 16;
    agg_to_lds<false>(As, hs4, dinv, row_ptr, col_src, bias4, r0, n, tid);
    __syncthreads();
    int wave = tid >> 6, lane = tid & 63;
    #pragma unroll
    for (int ii = 0; ii < 4; ++ii) {
        int li = wave * 4 + ii;
        int node = r0 + li;
        if (node >= n) continue;
        const float* row = As[li];
        float acc = 0.0f;
        if (lane < CDIM) {
            acc = bc[lane];
            for (int k = 0; k < FDIM; k += 4) {
                acc += row[k + 0] * Wc[(k + 0) * CDIM + lane];
                acc += row[k + 1] * Wc[(k + 1) * CDIM + lane];
                acc += row[k + 2] * Wc[(k + 2) * CDIM + lane];
                acc += row[k + 3] * Wc[(k + 3) * CDIM + lane];
            }
        }
        float v = (lane < CDIM) ? acc : -INFINITY;
        float m = v;
        for (int off = 32; off > 0; off >>= 1) m = fmaxf(m, __shfl_down(m, off));
        m = __shfl(m, 0);
        float e = (lane < CDIM) ? expf(v - m) : 0.0f;
        float s = e;
        for (int off = 32; off > 0; off >>= 1) s += __shfl_down(s, off);
        s = __shfl(s, 0);
        if (lane < CDIM) out[(size_t)node * CDIM + lane] = v - m - logf(s);
    }
}

// ---------------------------------------------------------------------------

extern "C" void kernel_launch(void* const* d_in, const int* in_sizes, int n_in,
                              void* d_out, int out_size, void* d_ws, size_t ws_size,
                              hipStream_t stream) {
    const float* x  = (const float*)d_in[0];
    const int*   ei = (const int*)d_in[1];
    const float* W1 = (const float*)d_in[2];
    const float* b1 = (const float*)d_in[3];
    const float* W2 = (const float*)d_in[4];
    const float* b2 = (const float*)d_in[5];
    const float* Wc = (const float*)d_in[6];
    const float* bc = (const float*)d_in[7];
    float* out = (float*)d_out;

    const int N = in_sizes[0] / FDIM;
    const int E = in_sizes[1] / 2;
    const int* srcp = ei;         // edge_index[0]
    const int* dstp = ei + E;     // edge_index[1]

    char* ws = (char*)d_ws;
    auto alloc = [&](size_t bytes) {
        char* p = ws;
        ws += (bytes + 255) & ~(size_t)255;
        return p;
    };
    int*   deg        = (int*)  alloc((size_t)N * 4);
    int*   row_ptr    = (int*)  alloc((size_t)(N + 1) * 4);
    float* dinv       = (float*)alloc((size_t)N * 4);
    int*   pos_within = (int*)  alloc((size_t)E * 4);
    int*   col_src    = (int*)  alloc((size_t)E * 4);
    float* hbuf       = (float*)alloc((size_t)N * FDIM * 4);
    float* hbuf2      = (float*)alloc((size_t)N * FDIM * 4);

    // Graph build
    k_init <<<(N + 255) / 256, 256, 0, stream>>>(deg, N);
    k_count<<<(E / 4 + 256) / 256, 256, 0, stream>>>(dstp, deg, pos_within, E);
    k_scan <<<1, 1024, 0, stream>>>(deg, row_ptr, dinv, N);

    // Layer-1 GEMM fused with CSR fill
    int gemm_blocks = (N + 31) / 32;
    int fill_blocks = (E / 4 + 256) / 256;
    k_mega<<<gemm_blocks + fill_blocks, 256, 0, stream>>>(
        x, W1, dinv, hbuf, N, srcp, dstp, row_ptr, pos_within, col_src, E,
        gemm_blocks);

    // agg1(+relu) -> @W2 -> hs2
    k_agg_gemm<<<(N + 15) / 16, 256, 0, stream>>>(
        (const float4*)hbuf, dinv, row_ptr, col_src, (const float4*)b1, W2,
        hbuf2, N);

    // agg2 -> classifier -> log_softmax
    k_agg_cls<<<(N + 15) / 16, 256, 0, stream>>>(
        (const float4*)hbuf2, dinv, row_ptr, col_src, (const float4*)b2, Wc,
        bc, out, N);
}